// Round 10
// baseline (532.584 us; speedup 1.0000x reference)
//
#include <hip/hip_runtime.h>

#define B 8
#define C 64
#define N 4096
#define O 64
#define KNN 20
#define PQ 4
#define BN_EPS 1e-5f
#define NEG_SLOPE 0.2f
#define NEG_INF -3.4e38f

typedef _Float16 f16x8 __attribute__((ext_vector_type(8)));
typedef float    f32x4 __attribute__((ext_vector_type(4)));
#define MFMA16(a, b, c) __builtin_amdgcn_mfma_f32_16x16x32_f16(a, b, c, 0, 0, 0)

// insert (r,m) into ascending-sorted top-KNN list with ids, dropping old min.
// precondition: r > d[0]. Tie-safe (insert below existing equal value).
__device__ __forceinline__ void sorted_insert(float (&d)[KNN], int (&id)[KNN],
                                              float r, int m) {
    bool c[KNN];
    #pragma unroll
    for (int j = 0; j < KNN; ++j) c[j] = d[j] < r;
    #pragma unroll
    for (int j = 0; j < KNN - 1; ++j) {
        d[j]  = __builtin_amdgcn_fmed3f(d[j], d[j + 1], r);
        id[j] = c[j + 1] ? id[j + 1] : (c[j] ? m : id[j]);
    }
    d[KNN - 1]  = c[KNN - 1] ? r : d[KNN - 1];
    id[KNN - 1] = c[KNN - 1] ? m : id[KNN - 1];
}

// score-only insert: 19 med3 + 1 max, branchless, exact no-op when r <= d[0].
__device__ __forceinline__ void insert_score(float (&d)[KNN], float r) {
    #pragma unroll
    for (int j = 0; j < KNN - 1; ++j)
        d[j] = __builtin_amdgcn_fmed3f(d[j], d[j + 1], r);
    d[KNN - 1] = fmaxf(d[KNN - 1], r);
}

// -------- K0: x (B,C,N) -> Xt (B,N,C) fp32, sq = ||x_n||^2, and AHL: f16 hi/lo
// frag-major: per 16-row group (4096 B): [term][khalf][quad][slot16][8 f16]
__global__ __launch_bounds__(256) void k_transpose(const float* __restrict__ x,
                                                   float* __restrict__ Xt,
                                                   float* __restrict__ sq,
                                                   char* __restrict__ AHL) {
    __shared__ float lds[C][65];
    int b    = blockIdx.x >> 6;
    int n0   = (blockIdx.x & 63) << 6;
    int lane = threadIdx.x & 63;
    int w    = threadIdx.x >> 6;
    #pragma unroll
    for (int i = 0; i < 16; ++i) {
        int c = w * 16 + i;
        lds[c][lane] = x[(size_t)b * C * N + (size_t)c * N + n0 + lane];
    }
    __syncthreads();
    #pragma unroll
    for (int i = 0; i < 16; ++i) {
        int nl = w * 16 + i;
        Xt[(size_t)b * N * C + (size_t)(n0 + nl) * C + lane] = lds[lane][nl];
    }
    // sq via quad-partial reduce: thread t owns n=t>>2, c-range (t&3)*16..+16.
    {
        int n_loc = threadIdx.x >> 2;
        int cg    = threadIdx.x & 3;
        float s = 0.f;
        #pragma unroll
        for (int ii = 0; ii < 16; ++ii) {
            float v = lds[cg * 16 + ii][n_loc];
            s = fmaf(v, v, s);
        }
        s += __shfl_xor(s, 1, 64);
        s += __shfl_xor(s, 2, 64);
        if (cg == 0) sq[b * N + n0 + n_loc] = s;
    }
    int s2  = threadIdx.x & 15;
    int rem = threadIdx.x >> 4;
    int qd  = rem & 3;
    int hh  = (rem >> 2) & 1;
    int tt  = rem >> 3;
    int kb  = hh * 32 + qd * 8;
    for (int i = 0; i < 4; ++i) {
        int rowl = i * 16 + s2;
        f16x8 pk;
        #pragma unroll
        for (int ii = 0; ii < 8; ++ii) {
            float v = lds[kb + ii][rowl];
            _Float16 hv = (_Float16)v;
            if (tt) hv = (_Float16)(v - (float)hv);
            pk[ii] = hv;
        }
        char* dst = AHL + ((size_t)b << 20) + (size_t)((n0 >> 4) + i) * 4096
                  + tt * 2048 + hh * 1024 + qd * 256 + s2 * 16;
        *(f16x8*)dst = pk;
    }
}

// -------- K1: a = X*(W1-W2)^T, bvec = X*W2^T
// b = bid&7: XCD-pinned (bid%8 = XCD round-robin) -> Xt[b] (1 MB) L2-local.
__global__ __launch_bounds__(256, 2) void k_ab(const float* __restrict__ Xt,
                                               const float* __restrict__ W,
                                               float* __restrict__ av,
                                               float* __restrict__ bv) {
    int b  = blockIdx.x & 7;
    int n0 = ((blockIdx.x >> 3) & 31) << 7;
    int o  = threadIdx.x & 63;
    int w  = __builtin_amdgcn_readfirstlane((int)(threadIdx.x >> 6));
    float wa[C], wb[C];
    #pragma unroll
    for (int c = 0; c < C; ++c) {
        float w1 = W[o * 2 * C + c];
        float w2 = W[o * 2 * C + C + c];
        wa[c] = w1 - w2;
        wb[c] = w2;
    }
    const float* xb = Xt + (size_t)b * N * C;
    for (int i = 0; i < 32; ++i) {
        int n = n0 + w * 32 + i;
        const float4* xr4 = (const float4*)(xb + (size_t)n * C);
        float aa = 0.f, bb = 0.f;
        #pragma unroll
        for (int c4 = 0; c4 < C / 4; ++c4) {
            float4 xv = xr4[c4];
            aa = fmaf(xv.x, wa[c4 * 4 + 0], aa);
            bb = fmaf(xv.x, wb[c4 * 4 + 0], bb);
            aa = fmaf(xv.y, wa[c4 * 4 + 1], aa);
            bb = fmaf(xv.y, wb[c4 * 4 + 1], bb);
            aa = fmaf(xv.z, wa[c4 * 4 + 2], aa);
            bb = fmaf(xv.z, wb[c4 * 4 + 2], bb);
            aa = fmaf(xv.w, wa[c4 * 4 + 3], aa);
            bb = fmaf(xv.w, wb[c4 * 4 + 3], bb);
        }
        size_t oidx = ((size_t)b * N + n) * O + o;
        av[oidx] = aa;
        bv[oidx] = bb;
    }
}

// -------- K2: TWO-PASS streaming MFMA kNN. Zero LDS, zero __syncthreads.
// 1-wave blocks, grid 4096, b = bid&7 (XCD-pinned), h = bit3, qg = bid>>4.
// R6-R9 established: selection is VALU-issue-bound; the queue+id-insert
// machinery has a ~29 instr/candidate floor while ids are carried in-scan.
//  PASS 1 (lean): branchless UNCONDITIONAL insert_score per candidate
//    (no-op when sc<=d[0]): 21 instr/cand, no compare, no queue, no shfl
//    (R7's phase-1 mistakes removed). Yields each lane's EXACT 20th score
//    T of its own 512 candidates.
//  PASS 2 (sparse): re-stream from L2, recompute scores bitwise-identically,
//    filter sc >= T -> exactly ~20 passes per lane total; queue + full
//    id-insert runs only on that trickle. Exact top-20 multiset per lane;
//    ties at T resolved by scan order (same policy as before).
// Tripwire: WRITE_SIZE ~10240 KB; launch_bounds(64,2) keeps VGPR cap high
// (R2: a clamped cap + big arrays = scratch catastrophe).
__global__ __launch_bounds__(64, 2) void k_knn(const char* __restrict__ AHL,
                                               const float* __restrict__ sq,
                                               float* __restrict__ pdg,
                                               int* __restrict__ pig) {
    int bid  = blockIdx.x;
    int qg   = bid >> 4;
    int b    = bid & 7;
    int h    = (bid >> 3) & 1;
    int lane = threadIdx.x & 63;
    int quad = lane >> 4;
    const char*  AHLb = AHL + ((size_t)b << 20);
    const float* sqb  = sq + b * N;
    int cbase0 = h * (N / 2);
    const char* Asrc = AHLb + (size_t)cbase0 * 256;

    // B-frags: this wave's query group qg: hi/lo x khalf (16 VGPRs)
    const char* qb = AHLb + (size_t)qg * 4096 + lane * 16;
    f16x8 bh0 = *(const f16x8*)(qb);
    f16x8 bh1 = *(const f16x8*)(qb + 1024);
    f16x8 bl0 = *(const f16x8*)(qb + 2048);
    f16x8 bl1 = *(const f16x8*)(qb + 3072);

    // ================= PASS 1: scores only, branchless =================
    float d[KNN];
    #pragma unroll
    for (int j = 0; j < KNN; ++j) d[j] = NEG_INF;

    const char* p0 = Asrc + lane * 16;
    f16x8 na0 = *(const f16x8*)(p0);
    f16x8 na1 = *(const f16x8*)(p0 + 1024);
    f16x8 na2 = *(const f16x8*)(p0 + 2048);
    f16x8 na3 = *(const f16x8*)(p0 + 3072);
    float4 nsq = *(const float4*)(sqb + cbase0 + quad * 4);

    #pragma unroll 1
    for (int it = 0; it < 128; ++it) {         // 16 cands per iter
        f16x8 a0 = na0, a1 = na1, a2 = na2, a3 = na3;
        float4 sqv = nsq;
        if (it + 1 < 128) {                    // issue next-iter loads early
            const char* p = Asrc + (size_t)(it + 1) * 4096 + lane * 16;
            na0 = *(const f16x8*)(p);
            na1 = *(const f16x8*)(p + 1024);
            na2 = *(const f16x8*)(p + 2048);
            na3 = *(const f16x8*)(p + 3072);
            nsq = *(const float4*)(sqb + cbase0 + (it + 1) * 16 + quad * 4);
        }
        f32x4 acc = {0.f, 0.f, 0.f, 0.f};
        acc = MFMA16(a0, bh0, acc);
        acc = MFMA16(a1, bh1, acc);
        acc = MFMA16(a0, bl0, acc);
        acc = MFMA16(a1, bl1, acc);
        acc = MFMA16(a2, bh0, acc);
        acc = MFMA16(a3, bh1, acc);
        #pragma unroll
        for (int r = 0; r < 4; ++r) {
            float sc = fmaf(2.f, acc[r],
                            -((r == 0) ? sqv.x : (r == 1) ? sqv.y
                                       : (r == 2) ? sqv.z : sqv.w));
            insert_score(d, sc);               // unconditional, branchless
        }
    }
    float T = d[0];   // lane's exact 20th-largest of its 512 candidates

    // ================= PASS 2: sparse index recovery =================
    float d2[KNN]; int id2[KNN];
    #pragma unroll
    for (int j = 0; j < KNN; ++j) { d2[j] = NEG_INF; id2[j] = 0; }
    float pv[PQ]; int pi[PQ]; int pc = 0;
    #pragma unroll
    for (int j = 0; j < PQ; ++j) { pv[j] = 0.f; pi[j] = 0; }

    na0 = *(const f16x8*)(p0);                 // re-prefetch (L2-resident)
    na1 = *(const f16x8*)(p0 + 1024);
    na2 = *(const f16x8*)(p0 + 2048);
    na3 = *(const f16x8*)(p0 + 3072);
    nsq = *(const float4*)(sqb + cbase0 + quad * 4);

    #pragma unroll 1
    for (int it = 0; it < 128; ++it) {
        f16x8 a0 = na0, a1 = na1, a2 = na2, a3 = na3;
        float4 sqv = nsq;
        if (it + 1 < 128) {
            const char* p = Asrc + (size_t)(it + 1) * 4096 + lane * 16;
            na0 = *(const f16x8*)(p);
            na1 = *(const f16x8*)(p + 1024);
            na2 = *(const f16x8*)(p + 2048);
            na3 = *(const f16x8*)(p + 3072);
            nsq = *(const float4*)(sqb + cbase0 + (it + 1) * 16 + quad * 4);
        }
        f32x4 acc = {0.f, 0.f, 0.f, 0.f};
        acc = MFMA16(a0, bh0, acc);
        acc = MFMA16(a1, bh1, acc);
        acc = MFMA16(a0, bl0, acc);
        acc = MFMA16(a1, bl1, acc);
        acc = MFMA16(a2, bh0, acc);
        acc = MFMA16(a3, bh1, acc);
        int c0 = cbase0 + it * 16 + quad * 4;  // lane's 4 cands (row=quad*4+r)
        #pragma unroll
        for (int r = 0; r < 4; ++r) {
            float sc = fmaf(2.f, acc[r],       // bitwise == pass-1 score
                            -((r == 0) ? sqv.x : (r == 1) ? sqv.y
                                       : (r == 2) ? sqv.z : sqv.w));
            if (sc >= T) {                     // ~20 passes per lane TOTAL
                #pragma unroll
                for (int j = 0; j < PQ; ++j) {
                    bool sel = (pc == j);
                    pv[j] = sel ? sc : pv[j];
                    pi[j] = sel ? (c0 + r) : pi[j];
                }
                ++pc;
            }
            if (__any(pc == PQ)) {             // rare drain
                #pragma unroll
                for (int j = 0; j < PQ; ++j)
                    if (j < pc && pv[j] > d2[0]) sorted_insert(d2, id2, pv[j], pi[j]);
                pc = 0;
            }
        }
    }
    #pragma unroll
    for (int j = 0; j < PQ; ++j)               // final flush
        if (j < pc && pv[j] > d2[0]) sorted_insert(d2, id2, pv[j], pi[j]);

    // in-wave quad-merge tournament via shuffles: 2,3 -> 0,1 then 1 -> 0
    #pragma unroll 1
    for (int step = 0; step < 2; ++step) {
        int off = (step == 0) ? 32 : 16;
        bool active = (step == 0) ? (quad < 2) : (quad == 0);
        for (int j = KNN - 1; j >= 0; --j) {   // descending; early-exit
            float rv = __shfl(d2[j], lane + off, 64);
            int   ri = __shfl(id2[j], lane + off, 64);
            bool ins = active && (rv > d2[0]);
            if (!__any(ins)) break;
            if (ins) sorted_insert(d2, id2, rv, ri);
        }
    }
    if (lane < 16) {
        size_t rr = (size_t)b * N + qg * 16 + lane;
        float* po = pdg + (rr * 2 + h) * KNN;
        int*   qo = pig + (rr * 2 + h) * KNN;
        #pragma unroll
        for (int j = 0; j < KNN; ++j) { po[j] = d2[j]; qo[j] = id2[j]; }
    }
}

// -------- K2b: merge the 2 sorted half-lists per query -> knn indices
// (split kernel: R8/R9 fusion attempts were 11-12 us slower than this)
__global__ __launch_bounds__(128) void k_merge(const float* __restrict__ pdg,
                                               const int* __restrict__ pig,
                                               int* __restrict__ knn) {
    __shared__ float sd[128][41];
    __shared__ int   si[128][41];
    int t = threadIdx.x;
    size_t rr = (size_t)blockIdx.x * 128 + t;
    const float* pr = pdg + rr * (2 * KNN);
    const int*   qr = pig + rr * (2 * KNN);
    #pragma unroll
    for (int j = 0; j < 2 * KNN; ++j) { sd[t][j] = pr[j]; si[t][j] = qr[j]; }
    int i = KNN - 1, j = KNN - 1;
    int* op = knn + rr * KNN;
    for (int o = 0; o < KNN; ++o) {
        bool t0 = (j < 0) || (i >= 0 && sd[t][i] >= sd[t][KNN + j]);
        op[o] = t0 ? si[t][i] : si[t][KNN + j];
        if (t0) --i; else --j;
    }
}

// -------- K3: out[b][o][n] = leaky(scale*(a[n][o] + max_k bvec[idx_k][o]) + bias)
// b = bid&7: XCD-pinned -> each XCD gathers only its own bv[b] (1 MB, L2-res).
__global__ __launch_bounds__(256) void k_out(const float* __restrict__ av,
                                             const float* __restrict__ bv,
                                             const int* __restrict__ knn,
                                             const float* __restrict__ gamma,
                                             const float* __restrict__ beta,
                                             const float* __restrict__ rmean,
                                             const float* __restrict__ rvar,
                                             float* __restrict__ out) {
    __shared__ float lds[64][65];
    int b    = blockIdx.x & 7;
    int n0   = (blockIdx.x >> 3) << 6;
    int lane = threadIdx.x & 63;
    int w    = __builtin_amdgcn_readfirstlane((int)(threadIdx.x >> 6));
    int o    = lane;
    float scale = gamma[o] * rsqrtf(rvar[o] + BN_EPS);
    float bias  = fmaf(-rmean[o], scale, beta[o]);
    const float* bvb = bv + (size_t)b * N * O;
    for (int i = 0; i < 16; ++i) {
        int n = n0 + w * 16 + i;
        const int* kn = knn + ((size_t)b * N + n) * KNN;
        float mx = -3.4e38f, mn = 3.4e38f;
        #pragma unroll
        for (int j = 0; j < KNN; ++j) {
            float v = bvb[(size_t)kn[j] * O + o];
            mx = fmaxf(mx, v);
            mn = fminf(mn, v);
        }
        float a   = av[((size_t)b * N + n) * O + o];
        float sel = (scale >= 0.f) ? (a + mx) : (a + mn);
        float y   = fmaf(sel, scale, bias);
        y = fmaxf(y, NEG_SLOPE * y);
        lds[o][w * 16 + i] = y;
    }
    __syncthreads();
    int r  = threadIdx.x >> 2;
    int c0 = (threadIdx.x & 3) << 4;
    float* ob = out + (size_t)b * O * N + (size_t)r * N + n0;
    #pragma unroll
    for (int j = 0; j < 16; j += 4) {
        float4 v;
        v.x = lds[r][c0 + j + 0];
        v.y = lds[r][c0 + j + 1];
        v.z = lds[r][c0 + j + 2];
        v.w = lds[r][c0 + j + 3];
        *(float4*)(ob + c0 + j) = v;
    }
}

extern "C" void kernel_launch(void* const* d_in, const int* in_sizes, int n_in,
                              void* d_out, int out_size, void* d_ws, size_t ws_size,
                              hipStream_t stream) {
    const float* x     = (const float*)d_in[0];
    const float* W     = (const float*)d_in[1];
    const float* gamma = (const float*)d_in[2];
    const float* beta  = (const float*)d_in[3];
    const float* rmean = (const float*)d_in[4];
    const float* rvar  = (const float*)d_in[5];
    float* out = (float*)d_out;

    char* wsb = (char*)d_ws;
    float* Xt  = (float*)(wsb);                 //  8 MB
    float* sqn = (float*)(wsb + 8388608);       //  128 KB
    float* av  = (float*)(wsb + 8519680);       //  8 MB
    float* bvv = (float*)(wsb + 16908288);      //  8 MB
    int*   knn = (int*)  (wsb + 25296896);      //  2.5 MB
    char*  AHL =         (wsb + 27918336);      //  8 MB f16 hi/lo frag-major
    float* pdg = (float*)(wsb + 36306944);      //  5.24 MB partial dists
    int*   pig = (int*)  (wsb + 41549824);      //  5.24 MB partial ids

    k_transpose<<<512, 256, 0, stream>>>(x, Xt, sqn, AHL);
    k_ab<<<256, 256, 0, stream>>>(Xt, W, av, bvv);
    k_knn<<<4096, 64, 0, stream>>>(AHL, sqn, pdg, pig);
    k_merge<<<256, 128, 0, stream>>>(pdg, pig, knn);
    k_out<<<512, 256, 0, stream>>>(av, bvv, knn, gamma, beta, rmean, rvar, out);
}

// Round 11
// 411.114 us; speedup vs baseline: 1.2955x; 1.2955x over previous
//
#include <hip/hip_runtime.h>

#define B 8
#define C 64
#define N 4096
#define O 64
#define KNN 20
#define PQ 4
#define BN_EPS 1e-5f
#define NEG_SLOPE 0.2f

typedef _Float16 f16x8 __attribute__((ext_vector_type(8)));
typedef float    f32x4 __attribute__((ext_vector_type(4)));
#define MFMA16(a, b, c) __builtin_amdgcn_mfma_f32_16x16x32_f16(a, b, c, 0, 0, 0)

// insert (r,m) into ascending-sorted top-KNN list, dropping old min d[0].
// precondition: r > d[0]. Tie-safe (insert below existing equal value).
// Branch-free parallel form: new_d[j] = med3(d[j], d[j+1], r); depth ~2.
__device__ __forceinline__ void sorted_insert(float (&d)[KNN], int (&id)[KNN],
                                              float r, int m) {
    bool c[KNN];
    #pragma unroll
    for (int j = 0; j < KNN; ++j) c[j] = d[j] < r;
    #pragma unroll
    for (int j = 0; j < KNN - 1; ++j) {
        d[j]  = __builtin_amdgcn_fmed3f(d[j], d[j + 1], r);
        id[j] = c[j + 1] ? id[j + 1] : (c[j] ? m : id[j]);
    }
    d[KNN - 1]  = c[KNN - 1] ? r : d[KNN - 1];
    id[KNN - 1] = c[KNN - 1] ? m : id[KNN - 1];
}

// -------- K0: x (B,C,N) -> Xt (B,N,C) fp32, sq = ||x_n||^2, and AHL: f16 hi/lo
// frag-major: per 16-row group (4096 B): [term][khalf][quad][slot16][8 f16]
__global__ __launch_bounds__(256) void k_transpose(const float* __restrict__ x,
                                                   float* __restrict__ Xt,
                                                   float* __restrict__ sq,
                                                   char* __restrict__ AHL) {
    __shared__ float lds[C][65];
    int b    = blockIdx.x >> 6;
    int n0   = (blockIdx.x & 63) << 6;
    int lane = threadIdx.x & 63;
    int w    = threadIdx.x >> 6;
    #pragma unroll
    for (int i = 0; i < 16; ++i) {
        int c = w * 16 + i;
        lds[c][lane] = x[(size_t)b * C * N + (size_t)c * N + n0 + lane];
    }
    __syncthreads();
    #pragma unroll
    for (int i = 0; i < 16; ++i) {
        int nl = w * 16 + i;
        Xt[(size_t)b * N * C + (size_t)(n0 + nl) * C + lane] = lds[lane][nl];
    }
    // sq via quad-partial reduce: thread t owns n=t>>2, c-range (t&3)*16..+16.
    {
        int n_loc = threadIdx.x >> 2;
        int cg    = threadIdx.x & 3;
        float s = 0.f;
        #pragma unroll
        for (int ii = 0; ii < 16; ++ii) {
            float v = lds[cg * 16 + ii][n_loc];
            s = fmaf(v, v, s);
        }
        s += __shfl_xor(s, 1, 64);
        s += __shfl_xor(s, 2, 64);
        if (cg == 0) sq[b * N + n0 + n_loc] = s;
    }
    int s2  = threadIdx.x & 15;
    int rem = threadIdx.x >> 4;
    int qd  = rem & 3;
    int hh  = (rem >> 2) & 1;
    int tt  = rem >> 3;
    int kb  = hh * 32 + qd * 8;
    for (int i = 0; i < 4; ++i) {
        int rowl = i * 16 + s2;
        f16x8 pk;
        #pragma unroll
        for (int ii = 0; ii < 8; ++ii) {
            float v = lds[kb + ii][rowl];
            _Float16 hv = (_Float16)v;
            if (tt) hv = (_Float16)(v - (float)hv);
            pk[ii] = hv;
        }
        char* dst = AHL + ((size_t)b << 20) + (size_t)((n0 >> 4) + i) * 4096
                  + tt * 2048 + hh * 1024 + qd * 256 + s2 * 16;
        *(f16x8*)dst = pk;
    }
}

// -------- K1: a = X*(W1-W2)^T, bvec = X*W2^T
// b = bid&7: XCD-pinned (bid%8 = XCD round-robin) -> Xt[b] (1 MB) L2-local.
__global__ __launch_bounds__(256, 2) void k_ab(const float* __restrict__ Xt,
                                               const float* __restrict__ W,
                                               float* __restrict__ av,
                                               float* __restrict__ bv) {
    int b  = blockIdx.x & 7;
    int n0 = ((blockIdx.x >> 3) & 31) << 7;
    int o  = threadIdx.x & 63;
    int w  = __builtin_amdgcn_readfirstlane((int)(threadIdx.x >> 6));
    float wa[C], wb[C];
    #pragma unroll
    for (int c = 0; c < C; ++c) {
        float w1 = W[o * 2 * C + c];
        float w2 = W[o * 2 * C + C + c];
        wa[c] = w1 - w2;
        wb[c] = w2;
    }
    const float* xb = Xt + (size_t)b * N * C;
    for (int i = 0; i < 32; ++i) {
        int n = n0 + w * 32 + i;
        const float4* xr4 = (const float4*)(xb + (size_t)n * C);
        float aa = 0.f, bb = 0.f;
        #pragma unroll
        for (int c4 = 0; c4 < C / 4; ++c4) {
            float4 xv = xr4[c4];
            aa = fmaf(xv.x, wa[c4 * 4 + 0], aa);
            bb = fmaf(xv.x, wb[c4 * 4 + 0], bb);
            aa = fmaf(xv.y, wa[c4 * 4 + 1], aa);
            bb = fmaf(xv.y, wb[c4 * 4 + 1], bb);
            aa = fmaf(xv.z, wa[c4 * 4 + 2], aa);
            bb = fmaf(xv.z, wb[c4 * 4 + 2], bb);
            aa = fmaf(xv.w, wa[c4 * 4 + 3], aa);
            bb = fmaf(xv.w, wb[c4 * 4 + 3], bb);
        }
        size_t oidx = ((size_t)b * N + n) * O + o;
        av[oidx] = aa;
        bv[oidx] = bb;
    }
}

// -------- K2: single-pass streaming MFMA kNN, QUARTER-split for occupancy.
// R6's exact instruction stream (proven floor ~250us at 4 waves/SIMD,
// VALUBusy 75%) -- this round supplies TLP, not fewer instructions:
//  - each wave scans N/4 = 1024 cands (256/lane) for its 16 queries;
//  - 2-wave blocks (128 thr), grid 4096 = exactly 16 blocks/CU -> 32
//    waves/CU resident (vs 16 with 1-wave blocks: the 16-workgroup/CU cap
//    was the hidden occupancy limit in R2/R6). VGPR ~60 <= 64 allows 8/SIMD.
//  - total instr count ~invariant (base x steps x waves constant; drains &
//    appends track total inserts).
// bid: b = bid&7 (XCD-pinned), qh = bit3, qg = bid>>4; wave w handles
// quarter q = qh*2 + w. Outputs 4 sorted 20-lists per query (pdg f32,
// pig u16 - ids < 4096).
// Tripwire: WRITE_SIZE ~15.7 MB (pdg 10.5 + pig 5.2); much larger => spill.
__global__ __launch_bounds__(128, 2) void k_knn(const char* __restrict__ AHL,
                                                const float* __restrict__ sq,
                                                float* __restrict__ pdg,
                                                unsigned short* __restrict__ pig) {
    int bid  = blockIdx.x;
    int qg   = bid >> 4;                 // 0..255 query group
    int b    = bid & 7;
    int qh   = (bid >> 3) & 1;
    int w    = __builtin_amdgcn_readfirstlane((int)(threadIdx.x >> 6));
    int q    = qh * 2 + w;               // quarter 0..3
    int lane = threadIdx.x & 63;
    int quad = lane >> 4;
    const char*  AHLb = AHL + ((size_t)b << 20);
    const float* sqb  = sq + b * N;
    int cbase0 = q * (N / 4);
    const char* Asrc = AHLb + (size_t)cbase0 * 256;

    // B-frags: this wave's query group qg: hi/lo x khalf (16 VGPRs)
    const char* qb = AHLb + (size_t)qg * 4096 + lane * 16;
    f16x8 bh0 = *(const f16x8*)(qb);
    f16x8 bh1 = *(const f16x8*)(qb + 1024);
    f16x8 bl0 = *(const f16x8*)(qb + 2048);
    f16x8 bl1 = *(const f16x8*)(qb + 3072);

    float d[KNN]; int id[KNN];
    float pv[PQ]; int pi[PQ]; int pc = 0;
    #pragma unroll
    for (int j = 0; j < PQ; ++j) { pv[j] = 0.f; pi[j] = 0; }

    // prefetch iter 0
    const char* p0 = Asrc + lane * 16;
    f16x8 na0 = *(const f16x8*)(p0);
    f16x8 na1 = *(const f16x8*)(p0 + 1024);
    f16x8 na2 = *(const f16x8*)(p0 + 2048);
    f16x8 na3 = *(const f16x8*)(p0 + 3072);
    float4 nsq = *(const float4*)(sqb + cbase0 + quad * 4);

    // ---- warm-fill: iters 0..4 (20 cands per lane) fill all KNN slots
    #pragma unroll
    for (int it = 0; it < 5; ++it) {
        f16x8 a0 = na0, a1 = na1, a2 = na2, a3 = na3;
        float4 sqv = nsq;
        {
            const char* p = Asrc + (size_t)(it + 1) * 4096 + lane * 16;
            na0 = *(const f16x8*)(p);
            na1 = *(const f16x8*)(p + 1024);
            na2 = *(const f16x8*)(p + 2048);
            na3 = *(const f16x8*)(p + 3072);
            nsq = *(const float4*)(sqb + cbase0 + (it + 1) * 16 + quad * 4);
        }
        f32x4 acc = {0.f, 0.f, 0.f, 0.f};
        acc = MFMA16(a0, bh0, acc);
        acc = MFMA16(a1, bh1, acc);
        acc = MFMA16(a0, bl0, acc);
        acc = MFMA16(a1, bl1, acc);
        acc = MFMA16(a2, bh0, acc);
        acc = MFMA16(a3, bh1, acc);
        int c0 = cbase0 + it * 16 + quad * 4;
        #pragma unroll
        for (int r = 0; r < 4; ++r) {
            float sc = fmaf(2.f, acc[r],
                            -((r == 0) ? sqv.x : (r == 1) ? sqv.y
                                       : (r == 2) ? sqv.z : sqv.w));
            d[it * 4 + r]  = sc;          // compile-time slot index
            id[it * 4 + r] = c0 + r;
        }
    }
    // one-time in-register bubble sort, ascending (compile-time indices)
    #pragma unroll
    for (int i = 0; i < KNN - 1; ++i) {
        #pragma unroll
        for (int j = 0; j < KNN - 1 - i; ++j) {
            bool sw = d[j] > d[j + 1];
            float tv = d[j]; int ti = id[j];
            d[j]      = sw ? d[j + 1] : d[j];
            id[j]     = sw ? id[j + 1] : id[j];
            d[j + 1]  = sw ? tv : d[j + 1];
            id[j + 1] = sw ? ti : id[j + 1];
        }
    }
    // shared threshold across the 4 quad-lanes serving this query
    float thr = d[0];
    thr = fmaxf(thr, __shfl_xor(thr, 16, 64));
    thr = fmaxf(thr, __shfl_xor(thr, 32, 64));

    #pragma unroll 1
    for (int it = 5; it < 64; ++it) {          // 16 cands per iter
        f16x8 a0 = na0, a1 = na1, a2 = na2, a3 = na3;
        float4 sqv = nsq;
        if (it + 1 < 64) {                     // issue next-iter loads early
            const char* p = Asrc + (size_t)(it + 1) * 4096 + lane * 16;
            na0 = *(const f16x8*)(p);
            na1 = *(const f16x8*)(p + 1024);
            na2 = *(const f16x8*)(p + 2048);
            na3 = *(const f16x8*)(p + 3072);
            nsq = *(const float4*)(sqb + cbase0 + (it + 1) * 16 + quad * 4);
        }
        f32x4 acc = {0.f, 0.f, 0.f, 0.f};
        acc = MFMA16(a0, bh0, acc);
        acc = MFMA16(a1, bh1, acc);
        acc = MFMA16(a0, bl0, acc);
        acc = MFMA16(a1, bl1, acc);
        acc = MFMA16(a2, bh0, acc);
        acc = MFMA16(a3, bh1, acc);
        int c0 = cbase0 + it * 16 + quad * 4;  // lane's 4 cands (row=quad*4+r)
        #pragma unroll
        for (int r = 0; r < 4; ++r) {
            float sc = fmaf(2.f, acc[r],
                            -((r == 0) ? sqv.x : (r == 1) ? sqv.y
                                       : (r == 2) ? sqv.z : sqv.w));
            if (sc > thr) {                    // global-ish filter
                #pragma unroll
                for (int j = 0; j < PQ; ++j) {
                    bool sel = (pc == j);
                    pv[j] = sel ? sc : pv[j];
                    pi[j] = sel ? (c0 + r) : pi[j];
                }
                ++pc;
            }
            if (__any(pc == PQ)) {             // drain all lanes in parallel
                #pragma unroll
                for (int j = 0; j < PQ; ++j)
                    if (j < pc && pv[j] > d[0]) sorted_insert(d, id, pv[j], pi[j]);
                pc = 0;
                float t = d[0];                // refresh shared threshold
                t = fmaxf(t, __shfl_xor(t, 16, 64));
                t = fmaxf(t, __shfl_xor(t, 32, 64));
                thr = fmaxf(thr, t);
            }
        }
    }
    #pragma unroll
    for (int j = 0; j < PQ; ++j)               // final flush
        if (j < pc && pv[j] > d[0]) sorted_insert(d, id, pv[j], pi[j]);

    // in-wave quad-merge tournament via shuffles: 2,3 -> 0,1 then 1 -> 0
    #pragma unroll 1
    for (int step = 0; step < 2; ++step) {
        int off = (step == 0) ? 32 : 16;
        bool active = (step == 0) ? (quad < 2) : (quad == 0);
        for (int j = KNN - 1; j >= 0; --j) {   // descending; early-exit
            float rv = __shfl(d[j], lane + off, 64);
            int   ri = __shfl(id[j], lane + off, 64);
            bool ins = active && (rv > d[0]);
            if (!__any(ins)) break;
            if (ins) sorted_insert(d, id, rv, ri);
        }
    }
    if (lane < 16) {
        size_t rr = (size_t)b * N + qg * 16 + lane;
        float*          po = pdg + (rr * 4 + q) * KNN;
        unsigned short* qo = pig + (rr * 4 + q) * KNN;
        #pragma unroll
        for (int j = 0; j < KNN; ++j) {
            po[j] = d[j];
            qo[j] = (unsigned short)id[j];
        }
    }
}

// -------- K2b: 4-way merge of the sorted quarter-lists per query -> knn.
// Pairwise in LDS: {q0,q1}->t1, {q2,q3}->t2, then t1,t2 -> output (desc).
// Ties prefer the earlier quarter (lower candidate index) at every level --
// same discipline as the proven 2-way version.
__global__ __launch_bounds__(64) void k_merge(const float* __restrict__ pdg,
                                              const unsigned short* __restrict__ pig,
                                              int* __restrict__ knn) {
    __shared__ float sd[64][121];
    __shared__ int   si[64][121];
    int t = threadIdx.x;
    size_t rr = (size_t)blockIdx.x * 64 + t;
    const float*          pr = pdg + rr * (4 * KNN);
    const unsigned short* qr = pig + rr * (4 * KNN);
    #pragma unroll
    for (int j = 0; j < 4 * KNN; ++j) { sd[t][j] = pr[j]; si[t][j] = qr[j]; }
    // pair merges (ascending, keep top KNN of each 2*KNN)
    #pragma unroll
    for (int pair = 0; pair < 2; ++pair) {
        int a0 = pair * 2 * KNN;
        int b0 = a0 + KNN;
        int o0 = 4 * KNN + pair * KNN;         // 80 or 100
        int i = KNN - 1, j = KNN - 1;
        #pragma unroll 1
        for (int k = KNN - 1; k >= 0; --k) {
            bool ta = (j < 0) || (i >= 0 && sd[t][a0 + i] >= sd[t][b0 + j]);
            sd[t][o0 + k] = ta ? sd[t][a0 + i] : sd[t][b0 + j];
            si[t][o0 + k] = ta ? si[t][a0 + i] : si[t][b0 + j];
            if (ta) --i; else --j;
        }
    }
    // final merge, output descending ids
    int i = KNN - 1, j = KNN - 1;
    int* op = knn + rr * KNN;
    #pragma unroll 1
    for (int o = 0; o < KNN; ++o) {
        bool ta = (j < 0) || (i >= 0 && sd[t][4 * KNN + i] >= sd[t][5 * KNN + j]);
        op[o] = ta ? si[t][4 * KNN + i] : si[t][5 * KNN + j];
        if (ta) --i; else --j;
    }
}

// -------- K3: out[b][o][n] = leaky(scale*(a[n][o] + max_k bvec[idx_k][o]) + bias)
// b = bid&7: XCD-pinned -> each XCD gathers only its own bv[b] (1 MB, L2-res).
__global__ __launch_bounds__(256) void k_out(const float* __restrict__ av,
                                             const float* __restrict__ bv,
                                             const int* __restrict__ knn,
                                             const float* __restrict__ gamma,
                                             const float* __restrict__ beta,
                                             const float* __restrict__ rmean,
                                             const float* __restrict__ rvar,
                                             float* __restrict__ out) {
    __shared__ float lds[64][65];
    int b    = blockIdx.x & 7;
    int n0   = (blockIdx.x >> 3) << 6;
    int lane = threadIdx.x & 63;
    int w    = __builtin_amdgcn_readfirstlane((int)(threadIdx.x >> 6));
    int o    = lane;
    float scale = gamma[o] * rsqrtf(rvar[o] + BN_EPS);
    float bias  = fmaf(-rmean[o], scale, beta[o]);
    const float* bvb = bv + (size_t)b * N * O;
    for (int i = 0; i < 16; ++i) {
        int n = n0 + w * 16 + i;
        const int* kn = knn + ((size_t)b * N + n) * KNN;
        float mx = -3.4e38f, mn = 3.4e38f;
        #pragma unroll
        for (int j = 0; j < KNN; ++j) {
            float v = bvb[(size_t)kn[j] * O + o];
            mx = fmaxf(mx, v);
            mn = fminf(mn, v);
        }
        float a   = av[((size_t)b * N + n) * O + o];
        float sel = (scale >= 0.f) ? (a + mx) : (a + mn);
        float y   = fmaf(sel, scale, bias);
        y = fmaxf(y, NEG_SLOPE * y);
        lds[o][w * 16 + i] = y;
    }
    __syncthreads();
    int r  = threadIdx.x >> 2;
    int c0 = (threadIdx.x & 3) << 4;
    float* ob = out + (size_t)b * O * N + (size_t)r * N + n0;
    #pragma unroll
    for (int j = 0; j < 16; j += 4) {
        float4 v;
        v.x = lds[r][c0 + j + 0];
        v.y = lds[r][c0 + j + 1];
        v.z = lds[r][c0 + j + 2];
        v.w = lds[r][c0 + j + 3];
        *(float4*)(ob + c0 + j) = v;
    }
}

extern "C" void kernel_launch(void* const* d_in, const int* in_sizes, int n_in,
                              void* d_out, int out_size, void* d_ws, size_t ws_size,
                              hipStream_t stream) {
    const float* x     = (const float*)d_in[0];
    const float* W     = (const float*)d_in[1];
    const float* gamma = (const float*)d_in[2];
    const float* beta  = (const float*)d_in[3];
    const float* rmean = (const float*)d_in[4];
    const float* rvar  = (const float*)d_in[5];
    float* out = (float*)d_out;

    char* wsb = (char*)d_ws;
    float* Xt  = (float*)(wsb);                 //  8 MB (dead after k_ab)
    unsigned short* pig = (unsigned short*)(wsb); // 5.24 MB, overlays Xt:
                                                //  written by k_knn, which is
                                                //  stream-ordered after k_ab's
                                                //  last read of Xt.
    float* sqn = (float*)(wsb + 8388608);       //  128 KB
    float* av  = (float*)(wsb + 8519680);       //  8 MB
    float* bvv = (float*)(wsb + 16908288);      //  8 MB
    int*   knn = (int*)  (wsb + 25296896);      //  2.5 MB
    char*  AHL =         (wsb + 27918336);      //  8 MB f16 hi/lo frag-major
    float* pdg = (float*)(wsb + 36306944);      // 10.49 MB (4 lists/query),
                                                //  ends at 46792704 = same
                                                //  total footprint as before.

    k_transpose<<<512, 256, 0, stream>>>(x, Xt, sqn, AHL);
    k_ab<<<256, 256, 0, stream>>>(Xt, W, av, bvv);
    k_knn<<<4096, 128, 0, stream>>>(AHL, sqn, pdg, pig);
    k_merge<<<512, 64, 0, stream>>>(pdg, pig, knn);
    k_out<<<512, 256, 0, stream>>>(av, bvv, knn, gamma, beta, rmean, rvar, out);
}

// Round 12
// 371.221 us; speedup vs baseline: 1.4347x; 1.1075x over previous
//
#include <hip/hip_runtime.h>

#define B 8
#define C 64
#define N 4096
#define O 64
#define KNN 20
#define PQ 4
#define BN_EPS 1e-5f
#define NEG_SLOPE 0.2f

typedef _Float16 f16x8 __attribute__((ext_vector_type(8)));
typedef float    f32x4 __attribute__((ext_vector_type(4)));
#define MFMA16(a, b, c) __builtin_amdgcn_mfma_f32_16x16x32_f16(a, b, c, 0, 0, 0)

// insert (r,m) into ascending-sorted top-KNN list, dropping old min d[0].
// precondition: r > d[0]. Tie-safe (insert below existing equal value).
// Branch-free parallel form: new_d[j] = med3(d[j], d[j+1], r); depth ~2.
__device__ __forceinline__ void sorted_insert(float (&d)[KNN], int (&id)[KNN],
                                              float r, int m) {
    bool c[KNN];
    #pragma unroll
    for (int j = 0; j < KNN; ++j) c[j] = d[j] < r;
    #pragma unroll
    for (int j = 0; j < KNN - 1; ++j) {
        d[j]  = __builtin_amdgcn_fmed3f(d[j], d[j + 1], r);
        id[j] = c[j + 1] ? id[j + 1] : (c[j] ? m : id[j]);
    }
    d[KNN - 1]  = c[KNN - 1] ? r : d[KNN - 1];
    id[KNN - 1] = c[KNN - 1] ? m : id[KNN - 1];
}

// -------- K0: x (B,C,N) -> Xt (B,N,C) fp32, sq = ||x_n||^2, and AHL: f16 hi/lo
// frag-major: per 16-row group (4096 B): [term][khalf][quad][slot16][8 f16]
__global__ __launch_bounds__(256) void k_transpose(const float* __restrict__ x,
                                                   float* __restrict__ Xt,
                                                   float* __restrict__ sq,
                                                   char* __restrict__ AHL) {
    __shared__ float lds[C][65];
    int b    = blockIdx.x >> 6;
    int n0   = (blockIdx.x & 63) << 6;
    int lane = threadIdx.x & 63;
    int w    = threadIdx.x >> 6;
    #pragma unroll
    for (int i = 0; i < 16; ++i) {
        int c = w * 16 + i;
        lds[c][lane] = x[(size_t)b * C * N + (size_t)c * N + n0 + lane];
    }
    __syncthreads();
    #pragma unroll
    for (int i = 0; i < 16; ++i) {
        int nl = w * 16 + i;
        Xt[(size_t)b * N * C + (size_t)(n0 + nl) * C + lane] = lds[lane][nl];
    }
    // sq via quad-partial reduce: thread t owns n=t>>2, c-range (t&3)*16..+16.
    {
        int n_loc = threadIdx.x >> 2;
        int cg    = threadIdx.x & 3;
        float s = 0.f;
        #pragma unroll
        for (int ii = 0; ii < 16; ++ii) {
            float v = lds[cg * 16 + ii][n_loc];
            s = fmaf(v, v, s);
        }
        s += __shfl_xor(s, 1, 64);
        s += __shfl_xor(s, 2, 64);
        if (cg == 0) sq[b * N + n0 + n_loc] = s;
    }
    int s2  = threadIdx.x & 15;
    int rem = threadIdx.x >> 4;
    int qd  = rem & 3;
    int hh  = (rem >> 2) & 1;
    int tt  = rem >> 3;
    int kb  = hh * 32 + qd * 8;
    for (int i = 0; i < 4; ++i) {
        int rowl = i * 16 + s2;
        f16x8 pk;
        #pragma unroll
        for (int ii = 0; ii < 8; ++ii) {
            float v = lds[kb + ii][rowl];
            _Float16 hv = (_Float16)v;
            if (tt) hv = (_Float16)(v - (float)hv);
            pk[ii] = hv;
        }
        char* dst = AHL + ((size_t)b << 20) + (size_t)((n0 >> 4) + i) * 4096
                  + tt * 2048 + hh * 1024 + qd * 256 + s2 * 16;
        *(f16x8*)dst = pk;
    }
}

// -------- K1: a = X*(W1-W2)^T, bvec = X*W2^T
// b = bid&7: XCD-pinned (bid%8 = XCD round-robin) -> Xt[b] (1 MB) L2-local.
__global__ __launch_bounds__(256, 2) void k_ab(const float* __restrict__ Xt,
                                               const float* __restrict__ W,
                                               float* __restrict__ av,
                                               float* __restrict__ bv) {
    int b  = blockIdx.x & 7;
    int n0 = ((blockIdx.x >> 3) & 31) << 7;
    int o  = threadIdx.x & 63;
    int w  = __builtin_amdgcn_readfirstlane((int)(threadIdx.x >> 6));
    float wa[C], wb[C];
    #pragma unroll
    for (int c = 0; c < C; ++c) {
        float w1 = W[o * 2 * C + c];
        float w2 = W[o * 2 * C + C + c];
        wa[c] = w1 - w2;
        wb[c] = w2;
    }
    const float* xb = Xt + (size_t)b * N * C;
    for (int i = 0; i < 32; ++i) {
        int n = n0 + w * 32 + i;
        const float4* xr4 = (const float4*)(xb + (size_t)n * C);
        float aa = 0.f, bb = 0.f;
        #pragma unroll
        for (int c4 = 0; c4 < C / 4; ++c4) {
            float4 xv = xr4[c4];
            aa = fmaf(xv.x, wa[c4 * 4 + 0], aa);
            bb = fmaf(xv.x, wb[c4 * 4 + 0], bb);
            aa = fmaf(xv.y, wa[c4 * 4 + 1], aa);
            bb = fmaf(xv.y, wb[c4 * 4 + 1], bb);
            aa = fmaf(xv.z, wa[c4 * 4 + 2], aa);
            bb = fmaf(xv.z, wb[c4 * 4 + 2], bb);
            aa = fmaf(xv.w, wa[c4 * 4 + 3], aa);
            bb = fmaf(xv.w, wb[c4 * 4 + 3], bb);
        }
        size_t oidx = ((size_t)b * N + n) * O + o;
        av[oidx] = aa;
        bv[oidx] = bb;
    }
}

// -------- K2: single-pass streaming MFMA kNN (measured-best config, R6).
// ONE WAVE PER BLOCK, grid 4096. b = bid&7 (XCD-pinned), h = bit3, qg=bid>>4.
// Wave owns queries qg*16..+16; lane quad scans its cand slice.
// Floor evidence (R6-R11): 9 structural variants (scheduling x4, drain
// tuning x3, two-pass x2, quarter-split TLP x1) all land at 248-253 us or
// worse; pure-issue bound ~190 us; leaf-size vs occupancy trades at ~unit
// rate. This config is the practical floor for this algorithm family.
//  - warm-fill + one bubble sort; shared quad threshold; med3 insert; PQ=4.
// Tripwire: WRITE_SIZE ~10240 KB; launch_bounds(64,2) keeps VGPR cap high
// (R2: (64,4) clamp -> d[]/id[] scratch spill -> 1 GB WRITE_SIZE).
__global__ __launch_bounds__(64, 2) void k_knn(const char* __restrict__ AHL,
                                               const float* __restrict__ sq,
                                               float* __restrict__ pdg,
                                               int* __restrict__ pig) {
    int bid  = blockIdx.x;
    int qg   = bid >> 4;
    int b    = bid & 7;
    int h    = (bid >> 3) & 1;
    int lane = threadIdx.x & 63;
    int quad = lane >> 4;
    const char*  AHLb = AHL + ((size_t)b << 20);
    const float* sqb  = sq + b * N;
    int cbase0 = h * (N / 2);
    const char* Asrc = AHLb + (size_t)cbase0 * 256;

    // B-frags: this wave's query group qg: hi/lo x khalf (16 VGPRs)
    const char* qb = AHLb + (size_t)qg * 4096 + lane * 16;
    f16x8 bh0 = *(const f16x8*)(qb);
    f16x8 bh1 = *(const f16x8*)(qb + 1024);
    f16x8 bl0 = *(const f16x8*)(qb + 2048);
    f16x8 bl1 = *(const f16x8*)(qb + 3072);

    float d[KNN]; int id[KNN];
    float pv[PQ]; int pi[PQ]; int pc = 0;
    #pragma unroll
    for (int j = 0; j < PQ; ++j) { pv[j] = 0.f; pi[j] = 0; }

    // prefetch iter 0
    const char* p0 = Asrc + lane * 16;
    f16x8 na0 = *(const f16x8*)(p0);
    f16x8 na1 = *(const f16x8*)(p0 + 1024);
    f16x8 na2 = *(const f16x8*)(p0 + 2048);
    f16x8 na3 = *(const f16x8*)(p0 + 3072);
    float4 nsq = *(const float4*)(sqb + cbase0 + quad * 4);

    // ---- warm-fill: iters 0..4 (20 cands per lane) fill all KNN slots
    #pragma unroll
    for (int it = 0; it < 5; ++it) {
        f16x8 a0 = na0, a1 = na1, a2 = na2, a3 = na3;
        float4 sqv = nsq;
        {
            const char* p = Asrc + (size_t)(it + 1) * 4096 + lane * 16;
            na0 = *(const f16x8*)(p);
            na1 = *(const f16x8*)(p + 1024);
            na2 = *(const f16x8*)(p + 2048);
            na3 = *(const f16x8*)(p + 3072);
            nsq = *(const float4*)(sqb + cbase0 + (it + 1) * 16 + quad * 4);
        }
        f32x4 acc = {0.f, 0.f, 0.f, 0.f};
        acc = MFMA16(a0, bh0, acc);
        acc = MFMA16(a1, bh1, acc);
        acc = MFMA16(a0, bl0, acc);
        acc = MFMA16(a1, bl1, acc);
        acc = MFMA16(a2, bh0, acc);
        acc = MFMA16(a3, bh1, acc);
        int c0 = cbase0 + it * 16 + quad * 4;
        #pragma unroll
        for (int r = 0; r < 4; ++r) {
            float sc = fmaf(2.f, acc[r],
                            -((r == 0) ? sqv.x : (r == 1) ? sqv.y
                                       : (r == 2) ? sqv.z : sqv.w));
            d[it * 4 + r]  = sc;          // compile-time slot index
            id[it * 4 + r] = c0 + r;
        }
    }
    // one-time in-register bubble sort, ascending (compile-time indices)
    #pragma unroll
    for (int i = 0; i < KNN - 1; ++i) {
        #pragma unroll
        for (int j = 0; j < KNN - 1 - i; ++j) {
            bool sw = d[j] > d[j + 1];
            float tv = d[j]; int ti = id[j];
            d[j]      = sw ? d[j + 1] : d[j];
            id[j]     = sw ? id[j + 1] : id[j];
            d[j + 1]  = sw ? tv : d[j + 1];
            id[j + 1] = sw ? ti : id[j + 1];
        }
    }
    // shared threshold across the 4 quad-lanes serving this query
    float thr = d[0];
    thr = fmaxf(thr, __shfl_xor(thr, 16, 64));
    thr = fmaxf(thr, __shfl_xor(thr, 32, 64));

    #pragma unroll 1
    for (int it = 5; it < 128; ++it) {         // 16 cands per iter
        f16x8 a0 = na0, a1 = na1, a2 = na2, a3 = na3;
        float4 sqv = nsq;
        if (it + 1 < 128) {                    // issue next-iter loads early
            const char* p = Asrc + (size_t)(it + 1) * 4096 + lane * 16;
            na0 = *(const f16x8*)(p);
            na1 = *(const f16x8*)(p + 1024);
            na2 = *(const f16x8*)(p + 2048);
            na3 = *(const f16x8*)(p + 3072);
            nsq = *(const float4*)(sqb + cbase0 + (it + 1) * 16 + quad * 4);
        }
        f32x4 acc = {0.f, 0.f, 0.f, 0.f};
        acc = MFMA16(a0, bh0, acc);
        acc = MFMA16(a1, bh1, acc);
        acc = MFMA16(a0, bl0, acc);
        acc = MFMA16(a1, bl1, acc);
        acc = MFMA16(a2, bh0, acc);
        acc = MFMA16(a3, bh1, acc);
        int c0 = cbase0 + it * 16 + quad * 4;  // lane's 4 cands (row=quad*4+r)
        #pragma unroll
        for (int r = 0; r < 4; ++r) {
            float sc = fmaf(2.f, acc[r],
                            -((r == 0) ? sqv.x : (r == 1) ? sqv.y
                                       : (r == 2) ? sqv.z : sqv.w));
            if (sc > thr) {                    // global-ish filter, rare pass
                #pragma unroll
                for (int j = 0; j < PQ; ++j) {
                    bool sel = (pc == j);
                    pv[j] = sel ? sc : pv[j];
                    pi[j] = sel ? (c0 + r) : pi[j];
                }
                ++pc;
            }
            if (__any(pc == PQ)) {             // drain all lanes in parallel
                #pragma unroll
                for (int j = 0; j < PQ; ++j)
                    if (j < pc && pv[j] > d[0]) sorted_insert(d, id, pv[j], pi[j]);
                pc = 0;
                float t = d[0];                // refresh shared threshold
                t = fmaxf(t, __shfl_xor(t, 16, 64));
                t = fmaxf(t, __shfl_xor(t, 32, 64));
                thr = fmaxf(thr, t);
            }
        }
    }
    #pragma unroll
    for (int j = 0; j < PQ; ++j)               // final flush
        if (j < pc && pv[j] > d[0]) sorted_insert(d, id, pv[j], pi[j]);

    // in-wave quad-merge tournament via shuffles: 2,3 -> 0,1 then 1 -> 0
    #pragma unroll 1
    for (int step = 0; step < 2; ++step) {
        int off = (step == 0) ? 32 : 16;
        bool active = (step == 0) ? (quad < 2) : (quad == 0);
        for (int j = KNN - 1; j >= 0; --j) {   // descending; early-exit
            float rv = __shfl(d[j], lane + off, 64);
            int   ri = __shfl(id[j], lane + off, 64);
            bool ins = active && (rv > d[0]);
            if (!__any(ins)) break;
            if (ins) sorted_insert(d, id, rv, ri);
        }
    }
    if (lane < 16) {
        size_t rr = (size_t)b * N + qg * 16 + lane;
        float* po = pdg + (rr * 2 + h) * KNN;
        int*   qo = pig + (rr * 2 + h) * KNN;
        #pragma unroll
        for (int j = 0; j < KNN; ++j) { po[j] = d[j]; qo[j] = id[j]; }
    }
}

// -------- K2b: merge the 2 sorted half-lists per query -> knn indices
// (split kernel: fusion into k_out measured slower twice, R8/R9)
__global__ __launch_bounds__(128) void k_merge(const float* __restrict__ pdg,
                                               const int* __restrict__ pig,
                                               int* __restrict__ knn) {
    __shared__ float sd[128][41];
    __shared__ int   si[128][41];
    int t = threadIdx.x;
    size_t rr = (size_t)blockIdx.x * 128 + t;
    const float* pr = pdg + rr * (2 * KNN);
    const int*   qr = pig + rr * (2 * KNN);
    #pragma unroll
    for (int j = 0; j < 2 * KNN; ++j) { sd[t][j] = pr[j]; si[t][j] = qr[j]; }
    int i = KNN - 1, j = KNN - 1;
    int* op = knn + rr * KNN;
    for (int o = 0; o < KNN; ++o) {
        bool t0 = (j < 0) || (i >= 0 && sd[t][i] >= sd[t][KNN + j]);
        op[o] = t0 ? si[t][i] : si[t][KNN + j];
        if (t0) --i; else --j;
    }
}

// -------- K3: out[b][o][n] = leaky(scale*(a[n][o] + max_k bvec[idx_k][o]) + bias)
// b = bid&7: XCD-pinned -> each XCD gathers only its own bv[b] (1 MB, L2-res).
__global__ __launch_bounds__(256) void k_out(const float* __restrict__ av,
                                             const float* __restrict__ bv,
                                             const int* __restrict__ knn,
                                             const float* __restrict__ gamma,
                                             const float* __restrict__ beta,
                                             const float* __restrict__ rmean,
                                             const float* __restrict__ rvar,
                                             float* __restrict__ out) {
    __shared__ float lds[64][65];
    int b    = blockIdx.x & 7;
    int n0   = (blockIdx.x >> 3) << 6;
    int lane = threadIdx.x & 63;
    int w    = __builtin_amdgcn_readfirstlane((int)(threadIdx.x >> 6));
    int o    = lane;
    float scale = gamma[o] * rsqrtf(rvar[o] + BN_EPS);
    float bias  = fmaf(-rmean[o], scale, beta[o]);
    const float* bvb = bv + (size_t)b * N * O;
    for (int i = 0; i < 16; ++i) {
        int n = n0 + w * 16 + i;
        const int* kn = knn + ((size_t)b * N + n) * KNN;
        float mx = -3.4e38f, mn = 3.4e38f;
        #pragma unroll
        for (int j = 0; j < KNN; ++j) {
            float v = bvb[(size_t)kn[j] * O + o];
            mx = fmaxf(mx, v);
            mn = fminf(mn, v);
        }
        float a   = av[((size_t)b * N + n) * O + o];
        float sel = (scale >= 0.f) ? (a + mx) : (a + mn);
        float y   = fmaf(sel, scale, bias);
        y = fmaxf(y, NEG_SLOPE * y);
        lds[o][w * 16 + i] = y;
    }
    __syncthreads();
    int r  = threadIdx.x >> 2;
    int c0 = (threadIdx.x & 3) << 4;
    float* ob = out + (size_t)b * O * N + (size_t)r * N + n0;
    #pragma unroll
    for (int j = 0; j < 16; j += 4) {
        float4 v;
        v.x = lds[r][c0 + j + 0];
        v.y = lds[r][c0 + j + 1];
        v.z = lds[r][c0 + j + 2];
        v.w = lds[r][c0 + j + 3];
        *(float4*)(ob + c0 + j) = v;
    }
}

extern "C" void kernel_launch(void* const* d_in, const int* in_sizes, int n_in,
                              void* d_out, int out_size, void* d_ws, size_t ws_size,
                              hipStream_t stream) {
    const float* x     = (const float*)d_in[0];
    const float* W     = (const float*)d_in[1];
    const float* gamma = (const float*)d_in[2];
    const float* beta  = (const float*)d_in[3];
    const float* rmean = (const float*)d_in[4];
    const float* rvar  = (const float*)d_in[5];
    float* out = (float*)d_out;

    char* wsb = (char*)d_ws;
    float* Xt  = (float*)(wsb);                 //  8 MB
    float* sqn = (float*)(wsb + 8388608);       //  128 KB
    float* av  = (float*)(wsb + 8519680);       //  8 MB
    float* bvv = (float*)(wsb + 16908288);      //  8 MB
    int*   knn = (int*)  (wsb + 25296896);      //  2.5 MB
    char*  AHL =         (wsb + 27918336);      //  8 MB f16 hi/lo frag-major
    float* pdg = (float*)(wsb + 36306944);      //  5.24 MB partial dists
    int*   pig = (int*)  (wsb + 41549824);      //  5.24 MB partial ids

    k_transpose<<<512, 256, 0, stream>>>(x, Xt, sqn, AHL);
    k_ab<<<256, 256, 0, stream>>>(Xt, W, av, bvv);
    k_knn<<<4096, 64, 0, stream>>>(AHL, sqn, pdg, pig);
    k_merge<<<256, 128, 0, stream>>>(pdg, pig, knn);
    k_out<<<512, 256, 0, stream>>>(av, bvv, knn, gamma, beta, rmean, rvar, out);
}